// Round 5
// baseline (6139.602 us; speedup 1.0000x reference)
//
#include <hip/hip_runtime.h>

// ---------- types / helpers ----------
typedef __attribute__((ext_vector_type(8))) __bf16 bf16x8;
typedef __attribute__((ext_vector_type(4))) float floatx4;

union ABFrag { uint4 u4; bf16x8 v; unsigned short s[8]; };

__device__ __forceinline__ float bf2f(unsigned short u) {
  return __uint_as_float(((unsigned int)u) << 16);
}
__device__ __forceinline__ unsigned short f2bf(float f) {
  unsigned int u = __float_as_uint(f);
  unsigned int r = 0x7fffu + ((u >> 16) & 1u);
  return (unsigned short)((u + r) >> 16);
}
__device__ __forceinline__ float sigmf(float x) { return 1.0f / (1.0f + expf(-x)); }

// dtype-agnostic input load: f32 ? float : bf16
__device__ __forceinline__ float ldi(const void* p, long i, bool f32) {
  return f32 ? ((const float*)p)[i] : bf2f(((const unsigned short*)p)[i]);
}

#define NNODES 32000
#define NEDGES 80000
#define NGRAPH 1000

#define MFMA_BF16 __builtin_amdgcn_mfma_f32_16x16x32_bf16

// ---------- dtype detect: bf16-read of fp32 data shows huge exponents ----------
__global__ __launch_bounds__(256) void detect_kernel(
    const unsigned short* __restrict__ nf, int* __restrict__ flag) {
  __shared__ float sm[256];
  float m = 0.f;
  for (int i = threadIdx.x; i < 4096; i += 256) {
    float v = fabsf(bf2f(nf[i]));
    if (isfinite(v)) m = fmaxf(m, v);
    else m = 1e30f;                      // inf/NaN bit pattern => fp32 data
  }
  sm[threadIdx.x] = m;
  __syncthreads();
  if (threadIdx.x == 0) {
    float mm = 0.f;
    for (int i = 0; i < 256; ++i) mm = fmaxf(mm, sm[i]);
    flag[0] = (mm > 1e6f) ? 1 : 0;
  }
}

// ---------- prep: transpose GRU weights to fp32 [192][64] ----------
__global__ __launch_bounds__(256) void prep_kernel(
    const int* __restrict__ dflag,
    const void* __restrict__ Wx, const void* __restrict__ Wh,
    const void* __restrict__ bx, const void* __restrict__ bh,
    const void* __restrict__ bconv,
    float* __restrict__ WxT, float* __restrict__ WhT,
    float* __restrict__ bxf, float* __restrict__ bhf, float* __restrict__ bconvf) {
  bool f32 = dflag[0] != 0;
  int idx = blockIdx.x * 256 + threadIdx.x;   // grid 48 -> 12288 = 192*64
  int j = idx >> 6, k = idx & 63;
  WxT[idx] = ldi(Wx, k * 192 + j, f32);
  WhT[idx] = ldi(Wh, k * 192 + j, f32);
  if (idx < 192) { bxf[idx] = ldi(bx, idx, f32); bhf[idx] = ldi(bh, idx, f32); }
  if (idx < 64) bconvf[idx] = ldi(bconv, idx, f32);
}

// ---------- node projection: h = relu(nf @ Wp + bp) ----------
__global__ __launch_bounds__(256) void nodeproj_kernel(
    const int* __restrict__ dflag,
    const void* __restrict__ nf, const void* __restrict__ Wp,
    const void* __restrict__ bp, float* __restrict__ hstate) {
  bool f32 = dflag[0] != 0;
  int lane = threadIdx.x & 63;
  int n = blockIdx.x * 4 + (threadIdx.x >> 6);
  float acc = ldi(bp, lane, f32);
  for (int k = 0; k < 74; ++k)
    acc += ldi(nf, (long)n * 74 + k, f32) * ldi(Wp, k * 64 + lane, f32);
  hstate[n * 64 + lane] = fmaxf(acc, 0.0f);
}

// ---------- We2T split: hi[col][k], lo[col][k] = split(We2[k][col]) ----------
__global__ __launch_bounds__(256) void we2t_kernel(
    const int* __restrict__ dflag,
    const void* __restrict__ We2,
    unsigned short* __restrict__ We2Thi, unsigned short* __restrict__ We2Tlo) {
  bool f32 = dflag[0] != 0;
  int idx = blockIdx.x * 256 + threadIdx.x;  // grid 2048 -> 524288
  int k = idx & 127, col = idx >> 7;
  float v = ldi(We2, (long)k * 4096 + col, f32);
  unsigned short hi = f2bf(v);
  We2Thi[idx] = hi;
  We2Tlo[idx] = f2bf(v - bf2f(hi));
}

// ---------- hb[n][o] = sum_d h[n][d] * be2[d*64+o] (fp32) ----------
__global__ __launch_bounds__(256) void hb_kernel(
    const int* __restrict__ dflag,
    const float* __restrict__ hstate, const void* __restrict__ be2,
    float* __restrict__ hb) {
  bool f32 = dflag[0] != 0;
  int lane = threadIdx.x & 63;
  int n = blockIdx.x * 4 + (threadIdx.x >> 6);
  const float* hrow = hstate + (size_t)n * 64;
  float acc = 0.f;
#pragma unroll 8
  for (int d = 0; d < 64; ++d) acc += hrow[d] * ldi(be2, d * 64 + lane, f32);
  hb[(size_t)n * 64 + lane] = acc;
}

// ---------- fused message passing, bf16x3 split precision ----------
// Stage 0: recompute U = relu(ef@We1+be1) fp32 for this block's 32 edges,
// split to hi/lo bf16 in LDS. Then per d: recompute W-tile via 3-term split
// MFMA (hi*hi + hi*lo + lo*hi, fp32 acc), fold h[src][d], accumulate msg;
// epilogue adds hb[src] and atomics into agg. Wave: 32 edges x 16 out-cols.
__global__ __launch_bounds__(256) void msg_fused_kernel(
    const int* __restrict__ dflag,
    const float* __restrict__ hstate,
    const void* __restrict__ ef, const void* __restrict__ We1,
    const void* __restrict__ be1,
    const unsigned short* __restrict__ We2Thi,
    const unsigned short* __restrict__ We2Tlo,
    const float* __restrict__ hb,
    const int* __restrict__ src, const int* __restrict__ dst,
    float* __restrict__ agg) {
  bool f32 = dflag[0] != 0;
  __shared__ float ef_s[384];
  __shared__ float we1_s[1536];
  __shared__ float be1_s[128];
  __shared__ unsigned short uhi[32][136];   // +8 pad: b128 reads 2-way max
  __shared__ unsigned short ulo[32][136];
  int t = threadIdx.x;
  int e0 = blockIdx.x * 32;                 // 2500 blocks

  // ---- stage 0: U in LDS ----
  for (int i = t; i < 384; i += 256) ef_s[i] = ldi(ef, (long)e0 * 12 + i, f32);
  for (int i = t; i < 1536; i += 256) we1_s[i] = ldi(We1, i, f32);
  if (t < 128) be1_s[t] = ldi(be1, t, f32);
  __syncthreads();
#pragma unroll
  for (int i = 0; i < 16; ++i) {
    int idx = t + i * 256;
    int row = idx >> 7, col = idx & 127;
    float acc = be1_s[col];
#pragma unroll
    for (int k = 0; k < 12; ++k) acc += ef_s[row * 12 + k] * we1_s[k * 128 + col];
    acc = fmaxf(acc, 0.f);
    unsigned short hi = f2bf(acc);
    uhi[row][col] = hi;
    ulo[row][col] = f2bf(acc - bf2f(hi));
  }
  __syncthreads();

  // ---- fragments ----
  int lane = t & 63, w = t >> 6;
  int o0 = w * 16;                          // wave's 16-col output slice
  int c = lane & 15, q = lane >> 4;
  ABFrag uAhi[4], uAlo[4], uBhi[4], uBlo[4];
#pragma unroll
  for (int kk = 0; kk < 4; ++kk) {
    uAhi[kk].u4 = *(const uint4*)&uhi[c][q * 8 + kk * 32];
    uAlo[kk].u4 = *(const uint4*)&ulo[c][q * 8 + kk * 32];
    uBhi[kk].u4 = *(const uint4*)&uhi[16 + c][q * 8 + kk * 32];
    uBlo[kk].u4 = *(const uint4*)&ulo[16 + c][q * 8 + kk * 32];
  }
  int eA = e0 + c, eB = e0 + 16 + c;
  int sA = src[eA], sB = src[eB];
  int dA = dst[eA], dB = dst[eB];
  const float* hA = hstate + (size_t)sA * 64;
  const float* hB = hstate + (size_t)sB * 64;
  floatx4 msgA = {0.f, 0.f, 0.f, 0.f}, msgB = {0.f, 0.f, 0.f, 0.f};

  // ---- d-loop ----
  for (int d = 0; d < 64; ++d) {
    long rbase = ((long)(d * 64 + o0 + c)) * 128 + q * 8;
    ABFrag ah[4], al[4];
#pragma unroll
    for (int kk = 0; kk < 4; ++kk) {
      ah[kk].u4 = *(const uint4*)(We2Thi + rbase + kk * 32);
      al[kk].u4 = *(const uint4*)(We2Tlo + rbase + kk * 32);
    }
    floatx4 wA = {0.f, 0.f, 0.f, 0.f}, wB = {0.f, 0.f, 0.f, 0.f};
#pragma unroll
    for (int kk = 0; kk < 4; ++kk) {
      wA = MFMA_BF16(ah[kk].v, uAhi[kk].v, wA, 0, 0, 0);
      wB = MFMA_BF16(ah[kk].v, uBhi[kk].v, wB, 0, 0, 0);
    }
#pragma unroll
    for (int kk = 0; kk < 4; ++kk) {
      wA = MFMA_BF16(ah[kk].v, uAlo[kk].v, wA, 0, 0, 0);
      wB = MFMA_BF16(ah[kk].v, uBlo[kk].v, wB, 0, 0, 0);
      wA = MFMA_BF16(al[kk].v, uAhi[kk].v, wA, 0, 0, 0);
      wB = MFMA_BF16(al[kk].v, uBhi[kk].v, wB, 0, 0, 0);
    }
    float hvA = hA[d];
    float hvB = hB[d];
#pragma unroll
    for (int r = 0; r < 4; ++r) {
      msgA[r] += hvA * wA[r];
      msgB[r] += hvB * wB[r];
    }
  }

  // ---- epilogue ----
  float* agA = agg + (size_t)dA * 64 + o0 + q * 4;
  float* agB = agg + (size_t)dB * 64 + o0 + q * 4;
  const float* hbA = hb + (size_t)sA * 64 + o0 + q * 4;
  const float* hbB = hb + (size_t)sB * 64 + o0 + q * 4;
#pragma unroll
  for (int r = 0; r < 4; ++r) {
    atomicAdd(agA + r, msgA[r] + hbA[r]);
    atomicAdd(agB + r, msgB[r] + hbB[r]);
  }
}

// ---------- GRU step (also zeroes agg for next step) ----------
__global__ __launch_bounds__(256) void gru_kernel(
    float* __restrict__ hstate, float* __restrict__ agg,
    const float* __restrict__ WxT, const float* __restrict__ WhT,
    const float* __restrict__ bxf, const float* __restrict__ bhf,
    const float* __restrict__ bconvf) {
  __shared__ float xs[64][65];
  __shared__ float hh[64][65];
  int t = threadIdx.x;
  int nb = blockIdx.x * 64;
#pragma unroll
  for (int i = 0; i < 16; ++i) {
    int idx = t + i * 256;
    int r = idx >> 6, c = idx & 63;
    int gidx = (nb + r) * 64 + c;
    float a = agg[gidx] + bconvf[c];
    agg[gidx] = 0.0f;
    xs[r][c] = a > 0.0f ? a : 0.0f;
    hh[r][c] = hstate[gidx];
  }
  __syncthreads();
  int lane = t & 63;
  int w = t >> 6;
  float x[64], hd[64];
#pragma unroll
  for (int k = 0; k < 64; ++k) { x[k] = xs[lane][k]; hd[k] = hh[lane][k]; }
  __syncthreads();
#pragma unroll 1
  for (int jj = 0; jj < 16; ++jj) {
    int j = __builtin_amdgcn_readfirstlane(w * 16 + jj);
    const float* wxr = WxT + j * 64;
    const float* wxz = WxT + (64 + j) * 64;
    const float* wxn = WxT + (128 + j) * 64;
    const float* whr = WhT + j * 64;
    const float* whz = WhT + (64 + j) * 64;
    const float* whn = WhT + (128 + j) * 64;
    float gxr = 0.f, gxz = 0.f, gxn = 0.f, ghr = 0.f, ghz = 0.f, ghn = 0.f;
#pragma unroll
    for (int k = 0; k < 64; ++k) {
      gxr += wxr[k] * x[k];
      gxz += wxz[k] * x[k];
      gxn += wxn[k] * x[k];
      ghr += whr[k] * hd[k];
      ghz += whz[k] * hd[k];
      ghn += whn[k] * hd[k];
    }
    float rg = sigmf(gxr + bxf[j] + ghr + bhf[j]);
    float zg = sigmf(gxz + bxf[64 + j] + ghz + bhf[64 + j]);
    float ng = tanhf(gxn + bxf[128 + j] + rg * (ghn + bhf[128 + j]));
    float hnew = (1.0f - zg) * ng + zg * hh[lane][j];
    xs[lane][j] = hnew;
  }
  __syncthreads();
#pragma unroll
  for (int i = 0; i < 16; ++i) {
    int idx = t + i * 256;
    int r = idx >> 6, c = idx & 63;
    hstate[(nb + r) * 64 + c] = xs[r][c];
  }
}

// ---------- Set2Set: 3-layer LSTM, one block per graph ----------
__global__ __launch_bounds__(256) void lstm_kernel(
    const int* __restrict__ dflag,
    const float* __restrict__ q_star, float* __restrict__ hsv, float* __restrict__ csv,
    float* __restrict__ qv,
    const void* Wx0, const void* Wh0, const void* bx0, const void* bh0,
    const void* Wx1, const void* Wh1, const void* bx1, const void* bh1,
    const void* Wx2, const void* Wh2, const void* bx2, const void* bh2) {
  bool f32 = dflag[0] != 0;
  __shared__ float xq[128];
  __shared__ float hh[64];
  __shared__ float gates[256];
  int g = blockIdx.x;
  int t = threadIdx.x;
  const void* Wx[3] = {Wx0, Wx1, Wx2};
  const void* Wh[3] = {Wh0, Wh1, Wh2};
  const void* bx[3] = {bx0, bx1, bx2};
  const void* bh[3] = {bh0, bh1, bh2};
  if (t < 128) xq[t] = q_star[g * 128 + t];
  for (int l = 0; l < 3; ++l) {
    int fi = (l == 0) ? 128 : 64;
    if (t < 64) hh[t] = hsv[l * 64000 + g * 64 + t];
    __syncthreads();
    float acc = ldi(bx[l], t, f32) + ldi(bh[l], t, f32);
    for (int k = 0; k < fi; ++k) acc += xq[k] * ldi(Wx[l], (long)k * 256 + t, f32);
    for (int k = 0; k < 64; ++k) acc += hh[k] * ldi(Wh[l], (long)k * 256 + t, f32);
    gates[t] = acc;
    __syncthreads();
    if (t < 64) {
      float ig = sigmf(gates[t]);
      float fg = sigmf(gates[64 + t]);
      float gg = tanhf(gates[128 + t]);
      float og = sigmf(gates[192 + t]);
      float c = fg * csv[l * 64000 + g * 64 + t] + ig * gg;
      float hn = og * tanhf(c);
      csv[l * 64000 + g * 64 + t] = c;
      hsv[l * 64000 + g * 64 + t] = hn;
      xq[t] = hn;
    }
    __syncthreads();
  }
  if (t < 64) qv[g * 64 + t] = xq[t];
}

// ---------- Set2Set: attention + readout (32 contiguous nodes per graph) ----------
__global__ __launch_bounds__(256) void attn_kernel(
    const float* __restrict__ hstate, const float* __restrict__ qv,
    float* __restrict__ q_star) {
  __shared__ float qs[64];
  __shared__ float al[32];
  __shared__ float rs[4][64];
  int g = blockIdx.x;
  int t = threadIdx.x;
  if (t < 64) qs[t] = qv[g * 64 + t];
  __syncthreads();
  int nl = t >> 3, part = t & 7;
  const float* hrow = hstate + (size_t)(g * 32 + nl) * 64 + part * 8;
  const float* qp = qs + part * 8;
  float p = 0.f;
#pragma unroll
  for (int k = 0; k < 8; ++k) p += hrow[k] * qp[k];
  p += __shfl_xor(p, 1, 64);
  p += __shfl_xor(p, 2, 64);
  p += __shfl_xor(p, 4, 64);
  if (part == 0) al[nl] = p;
  __syncthreads();
  if (t < 32) {
    float v = al[t];
    float m = v;
#pragma unroll
    for (int s2 = 1; s2 < 32; s2 <<= 1) m = fmaxf(m, __shfl_xor(m, s2, 32));
    float e = expf(v - m);
    float s = e;
#pragma unroll
    for (int s2 = 1; s2 < 32; s2 <<= 1) s += __shfl_xor(s, s2, 32);
    al[t] = e / s;
  }
  __syncthreads();
  int col = t & 63, grp = t >> 6;
  float acc = 0.f;
#pragma unroll
  for (int i = 0; i < 8; ++i) {
    int nn = grp * 8 + i;
    acc += al[nn] * hstate[(size_t)(g * 32 + nn) * 64 + col];
  }
  rs[grp][col] = acc;
  __syncthreads();
  if (t < 64) {
    float ro = rs[0][t] + rs[1][t] + rs[2][t] + rs[3][t];
    q_star[g * 128 + t] = qs[t];
    q_star[g * 128 + 64 + t] = ro;
  }
}

// ---------- head: pred = relu(q_star @ Wout1 + b) @ Wout2 + b; FP32 outputs ----------
__global__ __launch_bounds__(64) void head_kernel(
    const int* __restrict__ dflag,
    const float* __restrict__ q_star,
    const void* __restrict__ Wout1, const void* __restrict__ bout1,
    const void* __restrict__ Wout2, const void* __restrict__ bout2,
    float* __restrict__ out) {
  bool f32 = dflag[0] != 0;
  __shared__ float qs[128];
  int g = blockIdx.x;
  int t = threadIdx.x;
  qs[t] = q_star[g * 128 + t];
  qs[64 + t] = q_star[g * 128 + 64 + t];
  __syncthreads();
  float acc = ldi(bout1, t, f32);
#pragma unroll
  for (int k = 0; k < 128; ++k) acc += qs[k] * ldi(Wout1, k * 64 + t, f32);
  acc = fmaxf(acc, 0.0f);
  float p = acc * ldi(Wout2, t, f32);
#pragma unroll
  for (int m = 1; m < 64; m <<= 1) p += __shfl_xor(p, m, 64);
  if (t == 0) out[g] = p + ldi(bout2, 0, f32);
  out[1000 + g * 128 + t] = qs[t];
  out[1000 + g * 128 + 64 + t] = qs[64 + t];
}

// ---------- launch ----------
extern "C" void kernel_launch(void* const* d_in, const int* in_sizes, int n_in,
                              void* d_out, int out_size, void* d_ws, size_t ws_size,
                              hipStream_t stream) {
  (void)in_sizes; (void)n_in; (void)out_size; (void)ws_size;
  const void* node_feats = d_in[0];
  const void* edge_feats = d_in[1];
  const int* src = (const int*)d_in[2];
  const int* dst = (const int*)d_in[3];
  const void* Wp = d_in[5];
  const void* bp = d_in[6];
  const void* We1 = d_in[7];
  const void* be1 = d_in[8];
  const void* We2 = d_in[9];
  const void* be2 = d_in[10];
  const void* b_conv = d_in[11];
  const void* gWx = d_in[12];
  const void* gWh = d_in[13];
  const void* gbx = d_in[14];
  const void* gbh = d_in[15];
  const void* Wout1 = d_in[16];
  const void* bout1 = d_in[17];
  const void* Wout2 = d_in[18];
  const void* bout2 = d_in[19];

  // workspace layout (~29 MB; proven-mapped region >= 44.5 MB)
  int* dflag = (int*)d_ws;                                    // 64 floats reserved
  float* hstate = (float*)d_ws + 64;                          // 32000*64 f32
  float* agg = hstate + NNODES * 64;                          // 32000*64 f32
  float* hb = agg + NNODES * 64;                              // 32000*64 f32
  unsigned short* We2Thi = (unsigned short*)(hb + NNODES * 64);  // 4096*128 bf16
  unsigned short* We2Tlo = We2Thi + 4096 * 128;                  // 4096*128 bf16
  float* WxT = (float*)(We2Tlo + 4096 * 128);                 // 192*64 f32
  float* WhT = WxT + 12288;
  float* bxf = WhT + 12288;                                   // 192
  float* bhf = bxf + 192;                                     // 192
  float* bconvf = bhf + 192;                                  // 64
  float* q_star = bconvf + 64;                                // 1000*128
  float* hsv = q_star + 128000;                               // 3*1000*64
  float* csv = hsv + 192000;                                  // 3*1000*64
  float* qv = csv + 192000;                                   // 1000*64

  hipMemsetAsync(q_star, 0, (size_t)(128000 + 192000 + 192000) * sizeof(float), stream);
  hipMemsetAsync(agg, 0, (size_t)NNODES * 64 * sizeof(float), stream);

  detect_kernel<<<1, 256, 0, stream>>>((const unsigned short*)node_feats, dflag);
  prep_kernel<<<48, 256, 0, stream>>>(dflag, gWx, gWh, gbx, gbh, b_conv,
                                      WxT, WhT, bxf, bhf, bconvf);
  nodeproj_kernel<<<NNODES / 4, 256, 0, stream>>>(dflag, node_feats, Wp, bp, hstate);
  we2t_kernel<<<2048, 256, 0, stream>>>(dflag, We2, We2Thi, We2Tlo);

  for (int step = 0; step < 6; ++step) {
    hb_kernel<<<NNODES / 4, 256, 0, stream>>>(dflag, hstate, be2, hb);
    msg_fused_kernel<<<NEDGES / 32, 256, 0, stream>>>(
        dflag, hstate, edge_feats, We1, be1, We2Thi, We2Tlo, hb, src, dst, agg);
    gru_kernel<<<NNODES / 64, 256, 0, stream>>>(hstate, agg, WxT, WhT, bxf, bhf, bconvf);
  }
  for (int s = 0; s < 6; ++s) {
    lstm_kernel<<<NGRAPH, 256, 0, stream>>>(dflag, q_star, hsv, csv, qv,
        d_in[20], d_in[21], d_in[22], d_in[23],
        d_in[24], d_in[25], d_in[26], d_in[27],
        d_in[28], d_in[29], d_in[30], d_in[31]);
    attn_kernel<<<NGRAPH, 256, 0, stream>>>(hstate, qv, q_star);
  }
  head_kernel<<<NGRAPH, 64, 0, stream>>>(dflag, q_star, Wout1, bout1, Wout2, bout2,
                                         (float*)d_out);
}

// Round 6
// 2801.461 us; speedup vs baseline: 2.1916x; 2.1916x over previous
//
#include <hip/hip_runtime.h>

// ---------- types / helpers ----------
typedef __attribute__((ext_vector_type(8))) _Float16 f16x8;
typedef __attribute__((ext_vector_type(4))) float floatx4;

union HFrag { uint4 u4; f16x8 v; unsigned short s[8]; };
union HS { _Float16 h; unsigned short u; };

__device__ __forceinline__ float bf2f(unsigned short u) {
  return __uint_as_float(((unsigned int)u) << 16);
}
__device__ __forceinline__ float sigmf(float x) { return 1.0f / (1.0f + expf(-x)); }

// dtype-agnostic input load: f32 ? float : bf16
__device__ __forceinline__ float ldi(const void* p, long i, bool f32) {
  return f32 ? ((const float*)p)[i] : bf2f(((const unsigned short*)p)[i]);
}

#define NNODES 32000
#define NEDGES 80000
#define NGRAPH 1000

#define MFMA_F16 __builtin_amdgcn_mfma_f32_16x16x32_f16

// ---------- dtype detect: bf16-read of fp32 data shows huge exponents ----------
__global__ __launch_bounds__(256) void detect_kernel(
    const unsigned short* __restrict__ nf, int* __restrict__ flag) {
  __shared__ float sm[256];
  float m = 0.f;
  for (int i = threadIdx.x; i < 4096; i += 256) {
    float v = fabsf(bf2f(nf[i]));
    if (isfinite(v)) m = fmaxf(m, v);
    else m = 1e30f;
  }
  sm[threadIdx.x] = m;
  __syncthreads();
  if (threadIdx.x == 0) {
    float mm = 0.f;
    for (int i = 0; i < 256; ++i) mm = fmaxf(mm, sm[i]);
    flag[0] = (mm > 1e6f) ? 1 : 0;
  }
}

// ---------- prep: transpose GRU weights to fp32 [192][64] ----------
__global__ __launch_bounds__(256) void prep_kernel(
    const int* __restrict__ dflag,
    const void* __restrict__ Wx, const void* __restrict__ Wh,
    const void* __restrict__ bx, const void* __restrict__ bh,
    const void* __restrict__ bconv,
    float* __restrict__ WxT, float* __restrict__ WhT,
    float* __restrict__ bxf, float* __restrict__ bhf, float* __restrict__ bconvf) {
  bool f32 = dflag[0] != 0;
  int idx = blockIdx.x * 256 + threadIdx.x;
  int j = idx >> 6, k = idx & 63;
  WxT[idx] = ldi(Wx, k * 192 + j, f32);
  WhT[idx] = ldi(Wh, k * 192 + j, f32);
  if (idx < 192) { bxf[idx] = ldi(bx, idx, f32); bhf[idx] = ldi(bh, idx, f32); }
  if (idx < 64) bconvf[idx] = ldi(bconv, idx, f32);
}

// ---------- node projection: h = relu(nf @ Wp + bp) ----------
__global__ __launch_bounds__(256) void nodeproj_kernel(
    const int* __restrict__ dflag,
    const void* __restrict__ nf, const void* __restrict__ Wp,
    const void* __restrict__ bp, float* __restrict__ hstate) {
  bool f32 = dflag[0] != 0;
  int lane = threadIdx.x & 63;
  int n = blockIdx.x * 4 + (threadIdx.x >> 6);
  float acc = ldi(bp, lane, f32);
  for (int k = 0; k < 74; ++k)
    acc += ldi(nf, (long)n * 74 + k, f32) * ldi(Wp, k * 64 + lane, f32);
  hstate[n * 64 + lane] = fmaxf(acc, 0.0f);
}

// ---------- We2H[col][k] = fp16(We2[k][col])  (1 MB, done once) ----------
__global__ __launch_bounds__(256) void we2h_kernel(
    const int* __restrict__ dflag,
    const void* __restrict__ We2, unsigned short* __restrict__ We2H) {
  bool f32 = dflag[0] != 0;
  int idx = blockIdx.x * 256 + threadIdx.x;  // grid 2048 -> 524288
  int k = idx & 127, col = idx >> 7;
  HS z; z.h = (_Float16)ldi(We2, (long)k * 4096 + col, f32);
  We2H[idx] = z.u;
}

// ---------- hb[n][o] = sum_d h[n][d] * be2[d*64+o] (fp32) ----------
__global__ __launch_bounds__(256) void hb_kernel(
    const int* __restrict__ dflag,
    const float* __restrict__ hstate, const void* __restrict__ be2,
    float* __restrict__ hb) {
  bool f32 = dflag[0] != 0;
  int lane = threadIdx.x & 63;
  int n = blockIdx.x * 4 + (threadIdx.x >> 6);
  const float* hrow = hstate + (size_t)n * 64;
  float acc = 0.f;
#pragma unroll 8
  for (int d = 0; d < 64; ++d) acc += hrow[d] * ldi(be2, d * 64 + lane, f32);
  hb[(size_t)n * 64 + lane] = acc;
}

// ---------- fused message passing, fp16 MFMA ----------
// Block: 64 edges. Stage U=relu(ef@We1+be1) as fp16 and h[src] as fp32 in LDS.
// Per d: load A-frags (16 out-cols x K=128 of We2H, L2-resident 1MB), 4 MFMAs
// per edge-group (4 groups), fold h[src][d] from LDS, accumulate msg in VGPRs.
// Epilogue: atomics into agg (+ hb[src] bias term).
__global__ __launch_bounds__(256) void msg_fused_kernel(
    const int* __restrict__ dflag,
    const float* __restrict__ hstate,
    const void* __restrict__ ef, const void* __restrict__ We1,
    const void* __restrict__ be1,
    const unsigned short* __restrict__ We2H,
    const float* __restrict__ hb,
    const int* __restrict__ src, const int* __restrict__ dst,
    float* __restrict__ agg) {
  bool f32 = dflag[0] != 0;
  __shared__ float ef_s[768];
  __shared__ float we1_s[1536];
  __shared__ float be1_s[128];
  __shared__ int ssrc[64];
  __shared__ int sdst[64];
  __shared__ unsigned short u_s[64][136];   // fp16 U rows (+8 pad)
  __shared__ float h_s[64][65];             // h[src] rows (+1 pad)
  int t = threadIdx.x;
  int e0 = blockIdx.x * 64;                 // 1250 blocks

  // ---- stage inputs ----
  for (int i = t; i < 768; i += 256) ef_s[i] = ldi(ef, (long)e0 * 12 + i, f32);
  for (int i = t; i < 1536; i += 256) we1_s[i] = ldi(We1, i, f32);
  if (t < 128) be1_s[t] = ldi(be1, t, f32);
  if (t < 64) { ssrc[t] = src[e0 + t]; sdst[t] = dst[e0 + t]; }
  __syncthreads();

  // ---- U (fp16) and h_s ----
#pragma unroll
  for (int i = 0; i < 32; ++i) {            // 8192 = 64 edges x 128 cols
    int idx = t + i * 256;
    int row = idx >> 7, col = idx & 127;
    float acc = be1_s[col];
#pragma unroll
    for (int k = 0; k < 12; ++k) acc += ef_s[row * 12 + k] * we1_s[k * 128 + col];
    HS z; z.h = (_Float16)fmaxf(acc, 0.f);
    u_s[row][col] = z.u;
  }
#pragma unroll
  for (int i = 0; i < 16; ++i) {            // 4096 = 64 rows x 64 cols
    int idx = t + i * 256;
    int row = idx >> 6, col = idx & 63;
    h_s[row][col] = hstate[(size_t)ssrc[row] * 64 + col];
  }
  __syncthreads();

  // ---- fragments ----
  int lane = t & 63, w = t >> 6;
  int o0 = w * 16;                          // wave's 16-col output slice
  int c = lane & 15, q = lane >> 4;
  HFrag ub[4][4];
#pragma unroll
  for (int g = 0; g < 4; ++g)
#pragma unroll
    for (int kk = 0; kk < 4; ++kk)
      ub[g][kk].u4 = *(const uint4*)&u_s[g * 16 + c][q * 8 + kk * 32];
  floatx4 msg0 = {0.f,0.f,0.f,0.f}, msg1 = {0.f,0.f,0.f,0.f};
  floatx4 msg2 = {0.f,0.f,0.f,0.f}, msg3 = {0.f,0.f,0.f,0.f};
  const unsigned short* Abase = We2H + (size_t)(o0 + c) * 128 + q * 8;

  // ---- d-loop ----
#pragma unroll 2
  for (int d = 0; d < 64; ++d) {
    const unsigned short* arow = Abase + (size_t)d * 8192;
    HFrag a0, a1, a2, a3;
    a0.u4 = *(const uint4*)(arow + 0);
    a1.u4 = *(const uint4*)(arow + 32);
    a2.u4 = *(const uint4*)(arow + 64);
    a3.u4 = *(const uint4*)(arow + 96);
    float hv0 = h_s[c][d];
    float hv1 = h_s[16 + c][d];
    float hv2 = h_s[32 + c][d];
    float hv3 = h_s[48 + c][d];
    floatx4 w0 = {0.f,0.f,0.f,0.f}, w1 = {0.f,0.f,0.f,0.f};
    floatx4 w2 = {0.f,0.f,0.f,0.f}, w3 = {0.f,0.f,0.f,0.f};
    w0 = MFMA_F16(a0.v, ub[0][0].v, w0, 0, 0, 0);
    w1 = MFMA_F16(a0.v, ub[1][0].v, w1, 0, 0, 0);
    w2 = MFMA_F16(a0.v, ub[2][0].v, w2, 0, 0, 0);
    w3 = MFMA_F16(a0.v, ub[3][0].v, w3, 0, 0, 0);
    w0 = MFMA_F16(a1.v, ub[0][1].v, w0, 0, 0, 0);
    w1 = MFMA_F16(a1.v, ub[1][1].v, w1, 0, 0, 0);
    w2 = MFMA_F16(a1.v, ub[2][1].v, w2, 0, 0, 0);
    w3 = MFMA_F16(a1.v, ub[3][1].v, w3, 0, 0, 0);
    w0 = MFMA_F16(a2.v, ub[0][2].v, w0, 0, 0, 0);
    w1 = MFMA_F16(a2.v, ub[1][2].v, w1, 0, 0, 0);
    w2 = MFMA_F16(a2.v, ub[2][2].v, w2, 0, 0, 0);
    w3 = MFMA_F16(a2.v, ub[3][2].v, w3, 0, 0, 0);
    w0 = MFMA_F16(a3.v, ub[0][3].v, w0, 0, 0, 0);
    w1 = MFMA_F16(a3.v, ub[1][3].v, w1, 0, 0, 0);
    w2 = MFMA_F16(a3.v, ub[2][3].v, w2, 0, 0, 0);
    w3 = MFMA_F16(a3.v, ub[3][3].v, w3, 0, 0, 0);
#pragma unroll
    for (int r = 0; r < 4; ++r) {
      msg0[r] += hv0 * w0[r];
      msg1[r] += hv1 * w1[r];
      msg2[r] += hv2 * w2[r];
      msg3[r] += hv3 * w3[r];
    }
  }

  // ---- epilogue ----
#pragma unroll
  for (int g = 0; g < 4; ++g) {
    const floatx4& m = (g == 0) ? msg0 : (g == 1) ? msg1 : (g == 2) ? msg2 : msg3;
    int slot = g * 16 + c;
    int dn = sdst[slot], sn = ssrc[slot];
    float* ap = agg + (size_t)dn * 64 + o0 + q * 4;
    const float* hbp = hb + (size_t)sn * 64 + o0 + q * 4;
#pragma unroll
    for (int r = 0; r < 4; ++r) atomicAdd(ap + r, m[r] + hbp[r]);
  }
}

// ---------- GRU step (also zeroes agg for next step) ----------
__global__ __launch_bounds__(256) void gru_kernel(
    float* __restrict__ hstate, float* __restrict__ agg,
    const float* __restrict__ WxT, const float* __restrict__ WhT,
    const float* __restrict__ bxf, const float* __restrict__ bhf,
    const float* __restrict__ bconvf) {
  __shared__ float xs[64][65];
  __shared__ float hh[64][65];
  int t = threadIdx.x;
  int nb = blockIdx.x * 64;
#pragma unroll
  for (int i = 0; i < 16; ++i) {
    int idx = t + i * 256;
    int r = idx >> 6, c = idx & 63;
    int gidx = (nb + r) * 64 + c;
    float a = agg[gidx] + bconvf[c];
    agg[gidx] = 0.0f;
    xs[r][c] = a > 0.0f ? a : 0.0f;
    hh[r][c] = hstate[gidx];
  }
  __syncthreads();
  int lane = t & 63;
  int w = t >> 6;
  float x[64], hd[64];
#pragma unroll
  for (int k = 0; k < 64; ++k) { x[k] = xs[lane][k]; hd[k] = hh[lane][k]; }
  __syncthreads();
#pragma unroll 1
  for (int jj = 0; jj < 16; ++jj) {
    int j = __builtin_amdgcn_readfirstlane(w * 16 + jj);
    const float* wxr = WxT + j * 64;
    const float* wxz = WxT + (64 + j) * 64;
    const float* wxn = WxT + (128 + j) * 64;
    const float* whr = WhT + j * 64;
    const float* whz = WhT + (64 + j) * 64;
    const float* whn = WhT + (128 + j) * 64;
    float gxr = 0.f, gxz = 0.f, gxn = 0.f, ghr = 0.f, ghz = 0.f, ghn = 0.f;
#pragma unroll
    for (int k = 0; k < 64; ++k) {
      gxr += wxr[k] * x[k];
      gxz += wxz[k] * x[k];
      gxn += wxn[k] * x[k];
      ghr += whr[k] * hd[k];
      ghz += whz[k] * hd[k];
      ghn += whn[k] * hd[k];
    }
    float rg = sigmf(gxr + bxf[j] + ghr + bhf[j]);
    float zg = sigmf(gxz + bxf[64 + j] + ghz + bhf[64 + j]);
    float ng = tanhf(gxn + bxf[128 + j] + rg * (ghn + bhf[128 + j]));
    float hnew = (1.0f - zg) * ng + zg * hh[lane][j];
    xs[lane][j] = hnew;
  }
  __syncthreads();
#pragma unroll
  for (int i = 0; i < 16; ++i) {
    int idx = t + i * 256;
    int r = idx >> 6, c = idx & 63;
    hstate[(nb + r) * 64 + c] = xs[r][c];
  }
}

// ---------- Set2Set: 3-layer LSTM, one block per graph ----------
__global__ __launch_bounds__(256) void lstm_kernel(
    const int* __restrict__ dflag,
    const float* __restrict__ q_star, float* __restrict__ hsv, float* __restrict__ csv,
    float* __restrict__ qv,
    const void* Wx0, const void* Wh0, const void* bx0, const void* bh0,
    const void* Wx1, const void* Wh1, const void* bx1, const void* bh1,
    const void* Wx2, const void* Wh2, const void* bx2, const void* bh2) {
  bool f32 = dflag[0] != 0;
  __shared__ float xq[128];
  __shared__ float hh[64];
  __shared__ float gates[256];
  int g = blockIdx.x;
  int t = threadIdx.x;
  const void* Wx[3] = {Wx0, Wx1, Wx2};
  const void* Wh[3] = {Wh0, Wh1, Wh2};
  const void* bx[3] = {bx0, bx1, bx2};
  const void* bh[3] = {bh0, bh1, bh2};
  if (t < 128) xq[t] = q_star[g * 128 + t];
  for (int l = 0; l < 3; ++l) {
    int fi = (l == 0) ? 128 : 64;
    if (t < 64) hh[t] = hsv[l * 64000 + g * 64 + t];
    __syncthreads();
    float acc = ldi(bx[l], t, f32) + ldi(bh[l], t, f32);
    for (int k = 0; k < fi; ++k) acc += xq[k] * ldi(Wx[l], (long)k * 256 + t, f32);
    for (int k = 0; k < 64; ++k) acc += hh[k] * ldi(Wh[l], (long)k * 256 + t, f32);
    gates[t] = acc;
    __syncthreads();
    if (t < 64) {
      float ig = sigmf(gates[t]);
      float fg = sigmf(gates[64 + t]);
      float gg = tanhf(gates[128 + t]);
      float og = sigmf(gates[192 + t]);
      float c = fg * csv[l * 64000 + g * 64 + t] + ig * gg;
      float hn = og * tanhf(c);
      csv[l * 64000 + g * 64 + t] = c;
      hsv[l * 64000 + g * 64 + t] = hn;
      xq[t] = hn;
    }
    __syncthreads();
  }
  if (t < 64) qv[g * 64 + t] = xq[t];
}

// ---------- Set2Set: attention + readout ----------
__global__ __launch_bounds__(256) void attn_kernel(
    const float* __restrict__ hstate, const float* __restrict__ qv,
    float* __restrict__ q_star) {
  __shared__ float qs[64];
  __shared__ float al[32];
  __shared__ float rs[4][64];
  int g = blockIdx.x;
  int t = threadIdx.x;
  if (t < 64) qs[t] = qv[g * 64 + t];
  __syncthreads();
  int nl = t >> 3, part = t & 7;
  const float* hrow = hstate + (size_t)(g * 32 + nl) * 64 + part * 8;
  const float* qp = qs + part * 8;
  float p = 0.f;
#pragma unroll
  for (int k = 0; k < 8; ++k) p += hrow[k] * qp[k];
  p += __shfl_xor(p, 1, 64);
  p += __shfl_xor(p, 2, 64);
  p += __shfl_xor(p, 4, 64);
  if (part == 0) al[nl] = p;
  __syncthreads();
  if (t < 32) {
    float v = al[t];
    float m = v;
#pragma unroll
    for (int s2 = 1; s2 < 32; s2 <<= 1) m = fmaxf(m, __shfl_xor(m, s2, 32));
    float e = expf(v - m);
    float s = e;
#pragma unroll
    for (int s2 = 1; s2 < 32; s2 <<= 1) s += __shfl_xor(s, s2, 32);
    al[t] = e / s;
  }
  __syncthreads();
  int col = t & 63, grp = t >> 6;
  float acc = 0.f;
#pragma unroll
  for (int i = 0; i < 8; ++i) {
    int nn = grp * 8 + i;
    acc += al[nn] * hstate[(size_t)(g * 32 + nn) * 64 + col];
  }
  rs[grp][col] = acc;
  __syncthreads();
  if (t < 64) {
    float ro = rs[0][t] + rs[1][t] + rs[2][t] + rs[3][t];
    q_star[g * 128 + t] = qs[t];
    q_star[g * 128 + 64 + t] = ro;
  }
}

// ---------- head: FP32 outputs ----------
__global__ __launch_bounds__(64) void head_kernel(
    const int* __restrict__ dflag,
    const float* __restrict__ q_star,
    const void* __restrict__ Wout1, const void* __restrict__ bout1,
    const void* __restrict__ Wout2, const void* __restrict__ bout2,
    float* __restrict__ out) {
  bool f32 = dflag[0] != 0;
  __shared__ float qs[128];
  int g = blockIdx.x;
  int t = threadIdx.x;
  qs[t] = q_star[g * 128 + t];
  qs[64 + t] = q_star[g * 128 + 64 + t];
  __syncthreads();
  float acc = ldi(bout1, t, f32);
#pragma unroll
  for (int k = 0; k < 128; ++k) acc += qs[k] * ldi(Wout1, k * 64 + t, f32);
  acc = fmaxf(acc, 0.0f);
  float p = acc * ldi(Wout2, t, f32);
#pragma unroll
  for (int m = 1; m < 64; m <<= 1) p += __shfl_xor(p, m, 64);
  if (t == 0) out[g] = p + ldi(bout2, 0, f32);
  out[1000 + g * 128 + t] = qs[t];
  out[1000 + g * 128 + 64 + t] = qs[64 + t];
}

// ---------- launch ----------
extern "C" void kernel_launch(void* const* d_in, const int* in_sizes, int n_in,
                              void* d_out, int out_size, void* d_ws, size_t ws_size,
                              hipStream_t stream) {
  (void)in_sizes; (void)n_in; (void)out_size; (void)ws_size;
  const void* node_feats = d_in[0];
  const void* edge_feats = d_in[1];
  const int* src = (const int*)d_in[2];
  const int* dst = (const int*)d_in[3];
  const void* Wp = d_in[5];
  const void* bp = d_in[6];
  const void* We1 = d_in[7];
  const void* be1 = d_in[8];
  const void* We2 = d_in[9];
  const void* be2 = d_in[10];
  const void* b_conv = d_in[11];
  const void* gWx = d_in[12];
  const void* gWh = d_in[13];
  const void* gbx = d_in[14];
  const void* gbh = d_in[15];
  const void* Wout1 = d_in[16];
  const void* bout1 = d_in[17];
  const void* Wout2 = d_in[18];
  const void* bout2 = d_in[19];

  // workspace layout (~28 MB; proven-mapped region >= 44.5 MB)
  int* dflag = (int*)d_ws;                                    // 64 floats reserved
  float* hstate = (float*)d_ws + 64;                          // 32000*64 f32
  float* agg = hstate + NNODES * 64;                          // 32000*64 f32
  float* hb = agg + NNODES * 64;                              // 32000*64 f32
  unsigned short* We2H = (unsigned short*)(hb + NNODES * 64); // 4096*128 fp16
  float* WxT = (float*)(We2H + 4096 * 128);                   // 192*64 f32
  float* WhT = WxT + 12288;
  float* bxf = WhT + 12288;                                   // 192
  float* bhf = bxf + 192;                                     // 192
  float* bconvf = bhf + 192;                                  // 64
  float* q_star = bconvf + 64;                                // 1000*128
  float* hsv = q_star + 128000;                               // 3*1000*64
  float* csv = hsv + 192000;                                  // 3*1000*64
  float* qv = csv + 192000;                                   // 1000*64

  hipMemsetAsync(q_star, 0, (size_t)(128000 + 192000 + 192000) * sizeof(float), stream);
  hipMemsetAsync(agg, 0, (size_t)NNODES * 64 * sizeof(float), stream);

  detect_kernel<<<1, 256, 0, stream>>>((const unsigned short*)node_feats, dflag);
  prep_kernel<<<48, 256, 0, stream>>>(dflag, gWx, gWh, gbx, gbh, b_conv,
                                      WxT, WhT, bxf, bhf, bconvf);
  nodeproj_kernel<<<NNODES / 4, 256, 0, stream>>>(dflag, node_feats, Wp, bp, hstate);
  we2h_kernel<<<2048, 256, 0, stream>>>(dflag, We2, We2H);

  for (int step = 0; step < 6; ++step) {
    hb_kernel<<<NNODES / 4, 256, 0, stream>>>(dflag, hstate, be2, hb);
    msg_fused_kernel<<<NEDGES / 64, 256, 0, stream>>>(
        dflag, hstate, edge_feats, We1, be1, We2H, hb, src, dst, agg);
    gru_kernel<<<NNODES / 64, 256, 0, stream>>>(hstate, agg, WxT, WhT, bxf, bhf, bconvf);
  }
  for (int s = 0; s < 6; ++s) {
    lstm_kernel<<<NGRAPH, 256, 0, stream>>>(dflag, q_star, hsv, csv, qv,
        d_in[20], d_in[21], d_in[22], d_in[23],
        d_in[24], d_in[25], d_in[26], d_in[27],
        d_in[28], d_in[29], d_in[30], d_in[31]);
    attn_kernel<<<NGRAPH, 256, 0, stream>>>(hstate, qv, q_star);
  }
  head_kernel<<<NGRAPH, 64, 0, stream>>>(dflag, q_star, Wout1, bout1, Wout2, bout2,
                                         (float*)d_out);
}

// Round 7
// 2586.694 us; speedup vs baseline: 2.3735x; 1.0830x over previous
//
#include <hip/hip_runtime.h>

// ---------- types / helpers ----------
typedef __attribute__((ext_vector_type(8))) _Float16 f16x8;
typedef __attribute__((ext_vector_type(4))) float floatx4;

union HFrag { uint4 u4; f16x8 v; unsigned short s[8]; };
union HS { _Float16 h; unsigned short u; };

__device__ __forceinline__ float bf2f(unsigned short u) {
  return __uint_as_float(((unsigned int)u) << 16);
}
__device__ __forceinline__ float sigmf(float x) { return 1.0f / (1.0f + expf(-x)); }

// dtype-agnostic input load: f32 ? float : bf16
__device__ __forceinline__ float ldi(const void* p, long i, bool f32) {
  return f32 ? ((const float*)p)[i] : bf2f(((const unsigned short*)p)[i]);
}

// async global->LDS DMA, 16B per lane. LDS dest = wave-uniform base + lane*16.
__device__ __forceinline__ void dma16(unsigned short* lds, const unsigned short* g) {
  __builtin_amdgcn_global_load_lds(
      (const __attribute__((address_space(1))) unsigned int*)g,
      (__attribute__((address_space(3))) unsigned int*)lds,
      16, 0, 0);
}

#define NNODES 32000
#define NEDGES 80000
#define NGRAPH 1000

#define MFMA_F16 __builtin_amdgcn_mfma_f32_16x16x32_f16

// ---------- dtype detect ----------
__global__ __launch_bounds__(256) void detect_kernel(
    const unsigned short* __restrict__ nf, int* __restrict__ flag) {
  __shared__ float sm[256];
  float m = 0.f;
  for (int i = threadIdx.x; i < 4096; i += 256) {
    float v = fabsf(bf2f(nf[i]));
    if (isfinite(v)) m = fmaxf(m, v);
    else m = 1e30f;
  }
  sm[threadIdx.x] = m;
  __syncthreads();
  if (threadIdx.x == 0) {
    float mm = 0.f;
    for (int i = 0; i < 256; ++i) mm = fmaxf(mm, sm[i]);
    flag[0] = (mm > 1e6f) ? 1 : 0;
  }
}

// ---------- prep: transpose GRU weights to fp32 [192][64] ----------
__global__ __launch_bounds__(256) void prep_kernel(
    const int* __restrict__ dflag,
    const void* __restrict__ Wx, const void* __restrict__ Wh,
    const void* __restrict__ bx, const void* __restrict__ bh,
    const void* __restrict__ bconv,
    float* __restrict__ WxT, float* __restrict__ WhT,
    float* __restrict__ bxf, float* __restrict__ bhf, float* __restrict__ bconvf) {
  bool f32 = dflag[0] != 0;
  int idx = blockIdx.x * 256 + threadIdx.x;
  int j = idx >> 6, k = idx & 63;
  WxT[idx] = ldi(Wx, k * 192 + j, f32);
  WhT[idx] = ldi(Wh, k * 192 + j, f32);
  if (idx < 192) { bxf[idx] = ldi(bx, idx, f32); bhf[idx] = ldi(bh, idx, f32); }
  if (idx < 64) bconvf[idx] = ldi(bconv, idx, f32);
}

// ---------- node projection: h = relu(nf @ Wp + bp) ----------
__global__ __launch_bounds__(256) void nodeproj_kernel(
    const int* __restrict__ dflag,
    const void* __restrict__ nf, const void* __restrict__ Wp,
    const void* __restrict__ bp, float* __restrict__ hstate) {
  bool f32 = dflag[0] != 0;
  int lane = threadIdx.x & 63;
  int n = blockIdx.x * 4 + (threadIdx.x >> 6);
  float acc = ldi(bp, lane, f32);
  for (int k = 0; k < 74; ++k)
    acc += ldi(nf, (long)n * 74 + k, f32) * ldi(Wp, k * 64 + lane, f32);
  hstate[n * 64 + lane] = fmaxf(acc, 0.0f);
}

// ---------- We2Hsw: fp16, layout [d][o][cc][j], cc = (k/8) ^ (o&15) ----------
// XOR swizzle so the linear (DMA-friendly) layout is bank-conflict-free for
// the MFMA ds_read_b128 fragment pattern.
__global__ __launch_bounds__(256) void we2h_kernel(
    const int* __restrict__ dflag,
    const void* __restrict__ We2, unsigned short* __restrict__ We2Hsw) {
  bool f32 = dflag[0] != 0;
  int idx = blockIdx.x * 256 + threadIdx.x;  // grid 2048 -> 524288
  int j = idx & 7;
  int cc = (idx >> 3) & 15;
  int o = (idx >> 7) & 63;
  int d = idx >> 13;
  int k = ((cc ^ (o & 15)) << 3) | j;
  HS z; z.h = (_Float16)ldi(We2, (long)k * 4096 + d * 64 + o, f32);
  We2Hsw[idx] = z.u;
}

// ---------- CSR build (once per launch; dst is launch-invariant) ----------
__global__ __launch_bounds__(256) void count_kernel(
    const int* __restrict__ dst, int* __restrict__ cnt) {
  int e = blockIdx.x * 256 + threadIdx.x;
  if (e < NEDGES) atomicAdd(&cnt[dst[e]], 1);
}

__global__ __launch_bounds__(256) void scan_kernel(
    const int* __restrict__ cnt, int* __restrict__ row_ptr, int* __restrict__ cur) {
  __shared__ int part[256];
  int t = threadIdx.x;
  int base = t * 125;              // 256*125 = 32000
  int s = 0;
  for (int i = 0; i < 125; ++i) s += cnt[base + i];
  part[t] = s;
  __syncthreads();
  if (t == 0) {
    int run = 0;
    for (int i = 0; i < 256; ++i) { int v = part[i]; part[i] = run; run += v; }
  }
  __syncthreads();
  int run = part[t];
  for (int i = 0; i < 125; ++i) {
    row_ptr[base + i] = run;
    cur[base + i] = run;
    run += cnt[base + i];
  }
  if (t == 255) row_ptr[32000] = run;
}

__global__ __launch_bounds__(256) void fill_kernel(
    const int* __restrict__ dst, int* __restrict__ cur, int* __restrict__ eidx) {
  int e = blockIdx.x * 256 + threadIdx.x;
  if (e < NEDGES) { int p = atomicAdd(&cur[dst[e]], 1); eidx[p] = e; }
}

// ---------- hb[n][o] = sum_d h[n][d] * be2[d*64+o] (fp32) ----------
__global__ __launch_bounds__(256) void hb_kernel(
    const int* __restrict__ dflag,
    const float* __restrict__ hstate, const void* __restrict__ be2,
    float* __restrict__ hb) {
  bool f32 = dflag[0] != 0;
  int lane = threadIdx.x & 63;
  int n = blockIdx.x * 4 + (threadIdx.x >> 6);
  const float* hrow = hstate + (size_t)n * 64;
  float acc = 0.f;
#pragma unroll 8
  for (int d = 0; d < 64; ++d) acc += hrow[d] * ldi(be2, d * 64 + lane, f32);
  hb[(size_t)n * 64 + lane] = acc;
}

// ---------- fused message passing, fp16 MFMA, LDS-DMA double buffer ----------
// Block: 64 dst-sorted edges. U=relu(ef@We1+be1) fp16 + h[src] staged in LDS.
// d-loop: DMA slice d+1 (16KB swizzled We2) into wbuf[^], MFMA on wbuf[cur],
// barrier. Epilogue: plain float4 stores to msgbuf in sorted order (+hb[src]).
__global__ __launch_bounds__(256) void msg_fused_kernel(
    const int* __restrict__ dflag,
    const float* __restrict__ hstate,
    const void* __restrict__ ef, const void* __restrict__ We1,
    const void* __restrict__ be1,
    const unsigned short* __restrict__ We2Hsw,
    const float* __restrict__ hb,
    const int* __restrict__ src, const int* __restrict__ eidx,
    float* __restrict__ msgbuf) {
  bool f32 = dflag[0] != 0;
  __shared__ float ef_s[768];
  __shared__ float we1_s[1536];
  __shared__ float be1_s[128];
  __shared__ int seidx[64];
  __shared__ int ssrc[64];
  __shared__ __align__(16) unsigned short u_s[64][136];   // fp16 U rows (+8 pad)
  __shared__ float h_s[64][65];                           // h[src] rows (+1 pad)
  __shared__ __align__(16) unsigned short wbuf[2][8192];  // 2 x 16KB We2 d-slices
  int t = threadIdx.x;
  int e0 = blockIdx.x * 64;                 // 1250 blocks
  int lane = t & 63, w = t >> 6;

  // ---- stage edge list / weights ----
  if (t < 64) { int e = eidx[e0 + t]; seidx[t] = e; ssrc[t] = src[e]; }
  for (int i = t; i < 1536; i += 256) we1_s[i] = ldi(We1, i, f32);
  if (t < 128) be1_s[t] = ldi(be1, t, f32);
  __syncthreads();
  for (int i = t; i < 768; i += 256) {
    int slot = i / 12, k = i - slot * 12;
    ef_s[i] = ldi(ef, (long)seidx[slot] * 12 + k, f32);
  }
  __syncthreads();

  // ---- U (fp16) and h_s ----
#pragma unroll
  for (int i = 0; i < 32; ++i) {            // 8192 = 64 edges x 128 cols
    int idx = t + i * 256;
    int row = idx >> 7, col = idx & 127;
    float acc = be1_s[col];
#pragma unroll
    for (int k = 0; k < 12; ++k) acc += ef_s[row * 12 + k] * we1_s[k * 128 + col];
    HS z; z.h = (_Float16)fmaxf(acc, 0.f);
    u_s[row][col] = z.u;
  }
#pragma unroll
  for (int i = 0; i < 16; ++i) {            // 4096 = 64 rows x 64 cols
    int idx = t + i * 256;
    int row = idx >> 6, col = idx & 63;
    h_s[row][col] = hstate[(size_t)ssrc[row] * 64 + col];
  }
  __syncthreads();

  // ---- prefetch d-slice 0 (16KB: 4 waves x 4KB, 4 DMA calls of 1KB) ----
  {
    const unsigned short* g = We2Hsw + w * 2048 + lane * 8;
    unsigned short* l = &wbuf[0][w * 2048];
    dma16(l, g);
    dma16(l + 512, g + 512);
    dma16(l + 1024, g + 1024);
    dma16(l + 1536, g + 1536);
  }

  // ---- B fragments from u_s ----
  int o0 = w * 16;                          // wave's 16-col output slice
  int c = lane & 15, q = lane >> 4;
  HFrag ub[4][4];
#pragma unroll
  for (int g = 0; g < 4; ++g)
#pragma unroll
    for (int kk = 0; kk < 4; ++kk)
      ub[g][kk].u4 = *(const uint4*)&u_s[g * 16 + c][q * 8 + kk * 32];
  floatx4 msg0 = {0.f,0.f,0.f,0.f}, msg1 = {0.f,0.f,0.f,0.f};
  floatx4 msg2 = {0.f,0.f,0.f,0.f}, msg3 = {0.f,0.f,0.f,0.f};
  int rowb = (o0 + c) * 16;
  __syncthreads();                          // DMA slice 0 complete

  // ---- d-loop ----
  for (int d = 0; d < 64; ++d) {
    int cb = d & 1;
    if (d + 1 < 64) {
      const unsigned short* g = We2Hsw + (d + 1) * 8192 + w * 2048 + lane * 8;
      unsigned short* l = &wbuf[cb ^ 1][w * 2048];
      dma16(l, g);
      dma16(l + 512, g + 512);
      dma16(l + 1024, g + 1024);
      dma16(l + 1536, g + 1536);
    }
    const unsigned short* wb = wbuf[cb];
    HFrag a0, a1, a2, a3;
    a0.u4 = *(const uint4*)&wb[(rowb + ((0 * 4 + q) ^ c)) * 8];
    a1.u4 = *(const uint4*)&wb[(rowb + ((1 * 4 + q) ^ c)) * 8];
    a2.u4 = *(const uint4*)&wb[(rowb + ((2 * 4 + q) ^ c)) * 8];
    a3.u4 = *(const uint4*)&wb[(rowb + ((3 * 4 + q) ^ c)) * 8];
    float hv0 = h_s[c][d];
    float hv1 = h_s[16 + c][d];
    float hv2 = h_s[32 + c][d];
    float hv3 = h_s[48 + c][d];
    floatx4 w0 = {0.f,0.f,0.f,0.f}, w1 = {0.f,0.f,0.f,0.f};
    floatx4 w2 = {0.f,0.f,0.f,0.f}, w3 = {0.f,0.f,0.f,0.f};
    w0 = MFMA_F16(a0.v, ub[0][0].v, w0, 0, 0, 0);
    w1 = MFMA_F16(a0.v, ub[1][0].v, w1, 0, 0, 0);
    w2 = MFMA_F16(a0.v, ub[2][0].v, w2, 0, 0, 0);
    w3 = MFMA_F16(a0.v, ub[3][0].v, w3, 0, 0, 0);
    w0 = MFMA_F16(a1.v, ub[0][1].v, w0, 0, 0, 0);
    w1 = MFMA_F16(a1.v, ub[1][1].v, w1, 0, 0, 0);
    w2 = MFMA_F16(a1.v, ub[2][1].v, w2, 0, 0, 0);
    w3 = MFMA_F16(a1.v, ub[3][1].v, w3, 0, 0, 0);
    w0 = MFMA_F16(a2.v, ub[0][2].v, w0, 0, 0, 0);
    w1 = MFMA_F16(a2.v, ub[1][2].v, w1, 0, 0, 0);
    w2 = MFMA_F16(a2.v, ub[2][2].v, w2, 0, 0, 0);
    w3 = MFMA_F16(a2.v, ub[3][2].v, w3, 0, 0, 0);
    w0 = MFMA_F16(a3.v, ub[0][3].v, w0, 0, 0, 0);
    w1 = MFMA_F16(a3.v, ub[1][3].v, w1, 0, 0, 0);
    w2 = MFMA_F16(a3.v, ub[2][3].v, w2, 0, 0, 0);
    w3 = MFMA_F16(a3.v, ub[3][3].v, w3, 0, 0, 0);
#pragma unroll
    for (int r = 0; r < 4; ++r) {
      msg0[r] += hv0 * w0[r];
      msg1[r] += hv1 * w1[r];
      msg2[r] += hv2 * w2[r];
      msg3[r] += hv3 * w3[r];
    }
    __syncthreads();                        // drains DMA (d+1), guards wbuf reuse
  }

  // ---- epilogue: plain stores in sorted-edge order ----
#pragma unroll
  for (int g = 0; g < 4; ++g) {
    const floatx4& m = (g == 0) ? msg0 : (g == 1) ? msg1 : (g == 2) ? msg2 : msg3;
    int slot = g * 16 + c;
    int sn = ssrc[slot];
    const float* hbp = hb + (size_t)sn * 64 + o0 + q * 4;
    float4 st;
    st.x = m[0] + hbp[0];
    st.y = m[1] + hbp[1];
    st.z = m[2] + hbp[2];
    st.w = m[3] + hbp[3];
    *(float4*)(msgbuf + (size_t)(e0 + slot) * 64 + o0 + q * 4) = st;
  }
}

// ---------- GRU step with fused CSR gather ----------
__global__ __launch_bounds__(256) void gru_kernel(
    float* __restrict__ hstate, const float* __restrict__ msgbuf,
    const int* __restrict__ row_ptr,
    const float* __restrict__ WxT, const float* __restrict__ WhT,
    const float* __restrict__ bxf, const float* __restrict__ bhf,
    const float* __restrict__ bconvf) {
  __shared__ float xs[64][65];
  __shared__ float hh[64][65];
  int t = threadIdx.x;
  int nb = blockIdx.x * 64;
#pragma unroll
  for (int i = 0; i < 16; ++i) {
    int idx = t + i * 256;
    int r = idx >> 6, c = idx & 63;        // r is wave-uniform
    int n = nb + r;
    float a = bconvf[c];
    int p0 = row_ptr[n], p1 = row_ptr[n + 1];
    for (int p = p0; p < p1; ++p) a += msgbuf[(size_t)p * 64 + c];
    xs[r][c] = a > 0.0f ? a : 0.0f;
    hh[r][c] = hstate[(size_t)n * 64 + c];
  }
  __syncthreads();
  int lane = t & 63;
  int w = t >> 6;
  float x[64], hd[64];
#pragma unroll
  for (int k = 0; k < 64; ++k) { x[k] = xs[lane][k]; hd[k] = hh[lane][k]; }
  __syncthreads();
#pragma unroll 1
  for (int jj = 0; jj < 16; ++jj) {
    int j = __builtin_amdgcn_readfirstlane(w * 16 + jj);
    const float* wxr = WxT + j * 64;
    const float* wxz = WxT + (64 + j) * 64;
    const float* wxn = WxT + (128 + j) * 64;
    const float* whr = WhT + j * 64;
    const float* whz = WhT + (64 + j) * 64;
    const float* whn = WhT + (128 + j) * 64;
    float gxr = 0.f, gxz = 0.f, gxn = 0.f, ghr = 0.f, ghz = 0.f, ghn = 0.f;
#pragma unroll
    for (int k = 0; k < 64; ++k) {
      gxr += wxr[k] * x[k];
      gxz += wxz[k] * x[k];
      gxn += wxn[k] * x[k];
      ghr += whr[k] * hd[k];
      ghz += whz[k] * hd[k];
      ghn += whn[k] * hd[k];
    }
    float rg = sigmf(gxr + bxf[j] + ghr + bhf[j]);
    float zg = sigmf(gxz + bxf[64 + j] + ghz + bhf[64 + j]);
    float ng = tanhf(gxn + bxf[128 + j] + rg * (ghn + bhf[128 + j]));
    float hnew = (1.0f - zg) * ng + zg * hh[lane][j];
    xs[lane][j] = hnew;
  }
  __syncthreads();
#pragma unroll
  for (int i = 0; i < 16; ++i) {
    int idx = t + i * 256;
    int r = idx >> 6, c = idx & 63;
    hstate[(size_t)(nb + r) * 64 + c] = xs[r][c];
  }
}

// ---------- Set2Set: 3-layer LSTM, one block per graph ----------
__global__ __launch_bounds__(256) void lstm_kernel(
    const int* __restrict__ dflag,
    const float* __restrict__ q_star, float* __restrict__ hsv, float* __restrict__ csv,
    float* __restrict__ qv,
    const void* Wx0, const void* Wh0, const void* bx0, const void* bh0,
    const void* Wx1, const void* Wh1, const void* bx1, const void* bh1,
    const void* Wx2, const void* Wh2, const void* bx2, const void* bh2) {
  bool f32 = dflag[0] != 0;
  __shared__ float xq[128];
  __shared__ float hh[64];
  __shared__ float gates[256];
  int g = blockIdx.x;
  int t = threadIdx.x;
  const void* Wx[3] = {Wx0, Wx1, Wx2};
  const void* Wh[3] = {Wh0, Wh1, Wh2};
  const void* bx[3] = {bx0, bx1, bx2};
  const void* bh[3] = {bh0, bh1, bh2};
  if (t < 128) xq[t] = q_star[g * 128 + t];
  for (int l = 0; l < 3; ++l) {
    int fi = (l == 0) ? 128 : 64;
    if (t < 64) hh[t] = hsv[l * 64000 + g * 64 + t];
    __syncthreads();
    float acc = ldi(bx[l], t, f32) + ldi(bh[l], t, f32);
    for (int k = 0; k < fi; ++k) acc += xq[k] * ldi(Wx[l], (long)k * 256 + t, f32);
    for (int k = 0; k < 64; ++k) acc += hh[k] * ldi(Wh[l], (long)k * 256 + t, f32);
    gates[t] = acc;
    __syncthreads();
    if (t < 64) {
      float ig = sigmf(gates[t]);
      float fg = sigmf(gates[64 + t]);
      float gg = tanhf(gates[128 + t]);
      float og = sigmf(gates[192 + t]);
      float c = fg * csv[l * 64000 + g * 64 + t] + ig * gg;
      float hn = og * tanhf(c);
      csv[l * 64000 + g * 64 + t] = c;
      hsv[l * 64000 + g * 64 + t] = hn;
      xq[t] = hn;
    }
    __syncthreads();
  }
  if (t < 64) qv[g * 64 + t] = xq[t];
}

// ---------- Set2Set: attention + readout ----------
__global__ __launch_bounds__(256) void attn_kernel(
    const float* __restrict__ hstate, const float* __restrict__ qv,
    float* __restrict__ q_star) {
  __shared__ float qs[64];
  __shared__ float al[32];
  __shared__ float rs[4][64];
  int g = blockIdx.x;
  int t = threadIdx.x;
  if (t < 64) qs[t] = qv[g * 64 + t];
  __syncthreads();
  int nl = t >> 3, part = t & 7;
  const float* hrow = hstate + (size_t)(g * 32 + nl) * 64 + part * 8;
  const float* qp = qs + part * 8;
  float p = 0.f;
#pragma unroll
  for (int k = 0; k < 8; ++k) p += hrow[k] * qp[k];
  p += __shfl_xor(p, 1, 64);
  p += __shfl_xor(p, 2, 64);
  p += __shfl_xor(p, 4, 64);
  if (part == 0) al[nl] = p;
  __syncthreads();
  if (t < 32) {
    float v = al[t];
    float m = v;
#pragma unroll
    for (int s2 = 1; s2 < 32; s2 <<= 1) m = fmaxf(m, __shfl_xor(m, s2, 32));
    float e = expf(v - m);
    float s = e;
#pragma unroll
    for (int s2 = 1; s2 < 32; s2 <<= 1) s += __shfl_xor(s, s2, 32);
    al[t] = e / s;
  }
  __syncthreads();
  int col = t & 63, grp = t >> 6;
  float acc = 0.f;
#pragma unroll
  for (int i = 0; i < 8; ++i) {
    int nn = grp * 8 + i;
    acc += al[nn] * hstate[(size_t)(g * 32 + nn) * 64 + col];
  }
  rs[grp][col] = acc;
  __syncthreads();
  if (t < 64) {
    float ro = rs[0][t] + rs[1][t] + rs[2][t] + rs[3][t];
    q_star[g * 128 + t] = qs[t];
    q_star[g * 128 + 64 + t] = ro;
  }
}

// ---------- head: FP32 outputs ----------
__global__ __launch_bounds__(64) void head_kernel(
    const int* __restrict__ dflag,
    const float* __restrict__ q_star,
    const void* __restrict__ Wout1, const void* __restrict__ bout1,
    const void* __restrict__ Wout2, const void* __restrict__ bout2,
    float* __restrict__ out) {
  bool f32 = dflag[0] != 0;
  __shared__ float qs[128];
  int g = blockIdx.x;
  int t = threadIdx.x;
  qs[t] = q_star[g * 128 + t];
  qs[64 + t] = q_star[g * 128 + 64 + t];
  __syncthreads();
  float acc = ldi(bout1, t, f32);
#pragma unroll
  for (int k = 0; k < 128; ++k) acc += qs[k] * ldi(Wout1, k * 64 + t, f32);
  acc = fmaxf(acc, 0.0f);
  float p = acc * ldi(Wout2, t, f32);
#pragma unroll
  for (int m = 1; m < 64; m <<= 1) p += __shfl_xor(p, m, 64);
  if (t == 0) out[g] = p + ldi(bout2, 0, f32);
  out[1000 + g * 128 + t] = qs[t];
  out[1000 + g * 128 + 64 + t] = qs[64 + t];
}

// ---------- launch ----------
extern "C" void kernel_launch(void* const* d_in, const int* in_sizes, int n_in,
                              void* d_out, int out_size, void* d_ws, size_t ws_size,
                              hipStream_t stream) {
  (void)in_sizes; (void)n_in; (void)out_size; (void)ws_size;
  const void* node_feats = d_in[0];
  const void* edge_feats = d_in[1];
  const int* src = (const int*)d_in[2];
  const int* dst = (const int*)d_in[3];
  const void* Wp = d_in[5];
  const void* bp = d_in[6];
  const void* We1 = d_in[7];
  const void* be1 = d_in[8];
  const void* We2 = d_in[9];
  const void* be2 = d_in[10];
  const void* b_conv = d_in[11];
  const void* gWx = d_in[12];
  const void* gWh = d_in[13];
  const void* gbx = d_in[14];
  const void* gbh = d_in[15];
  const void* Wout1 = d_in[16];
  const void* bout1 = d_in[17];
  const void* Wout2 = d_in[18];
  const void* bout2 = d_in[19];

  // workspace layout (~41 MB; proven-mapped region >= 44.5 MB)
  int* dflag = (int*)d_ws;                                    // 64 ints reserved
  float* hstate = (float*)d_ws + 64;                          // 32000*64 f32
  float* hb = hstate + NNODES * 64;                           // 32000*64 f32
  float* msgbuf = hb + NNODES * 64;                           // 80000*64 f32
  unsigned short* We2Hsw = (unsigned short*)(msgbuf + (size_t)NEDGES * 64); // 524288 fp16
  float* WxT = (float*)(We2Hsw + 524288);                     // 192*64 f32
  float* WhT = WxT + 12288;
  float* bxf = WhT + 12288;                                   // 192
  float* bhf = bxf + 192;                                     // 192
  float* bconvf = bhf + 192;                                  // 64
  float* q_star = bconvf + 64;                                // 1000*128
  float* hsv = q_star + 128000;                               // 3*1000*64
  float* csv = hsv + 192000;                                  // 3*1000*64
  float* qv = csv + 192000;                                   // 1000*64
  int* row_ptr = (int*)(qv + 64000);                          // 32001
  int* cur = row_ptr + 32001;                                 // 32000
  int* cnt = cur + 32000;                                     // 32000
  int* eidx = cnt + 32000;                                    // 80000

  hipMemsetAsync(q_star, 0, (size_t)(128000 + 192000 + 192000) * sizeof(float), stream);
  hipMemsetAsync(cnt, 0, (size_t)NNODES * sizeof(int), stream);

  detect_kernel<<<1, 256, 0, stream>>>((const unsigned short*)node_feats, dflag);
  prep_kernel<<<48, 256, 0, stream>>>(dflag, gWx, gWh, gbx, gbh, b_conv,
                                      WxT, WhT, bxf, bhf, bconvf);
  nodeproj_kernel<<<NNODES / 4, 256, 0, stream>>>(dflag, node_feats, Wp, bp, hstate);
  we2h_kernel<<<2048, 256, 0, stream>>>(dflag, We2, We2Hsw);

  count_kernel<<<(NEDGES + 255) / 256, 256, 0, stream>>>(dst, cnt);
  scan_kernel<<<1, 256, 0, stream>>>(cnt, row_ptr, cur);
  fill_kernel<<<(NEDGES + 255) / 256, 256, 0, stream>>>(dst, cur, eidx);

  for (int step = 0; step < 6; ++step) {
    hb_kernel<<<NNODES / 4, 256, 0, stream>>>(dflag, hstate, be2, hb);
    msg_fused_kernel<<<NEDGES / 64, 256, 0, stream>>>(
        dflag, hstate, edge_feats, We1, be1, We2Hsw, hb, src, eidx, msgbuf);
    gru_kernel<<<NNODES / 64, 256, 0, stream>>>(hstate, msgbuf, row_ptr,
                                                WxT, WhT, bxf, bhf, bconvf);
  }
  for (int s = 0; s < 6; ++s) {
    lstm_kernel<<<NGRAPH, 256, 0, stream>>>(dflag, q_star, hsv, csv, qv,
        d_in[20], d_in[21], d_in[22], d_in[23],
        d_in[24], d_in[25], d_in[26], d_in[27],
        d_in[28], d_in[29], d_in[30], d_in[31]);
    attn_kernel<<<NGRAPH, 256, 0, stream>>>(hstate, qv, q_star);
  }
  head_kernel<<<NGRAPH, 64, 0, stream>>>(dflag, q_star, Wout1, bout1, Wout2, bout2,
                                         (float*)d_out);
}